// Round 11
// baseline (438.915 us; speedup 1.0000x reference)
//
#include <hip/hip_runtime.h>
#include <hip/hip_fp16.h>
#include <math.h>

#define NN 100000
#define NE 1600000

// ---------- CSR build: hist with rank recording ----------
__global__ void k_hist(const int* __restrict__ ei, int* __restrict__ counts,
                       int* __restrict__ rank) {
    int e = blockIdx.x * blockDim.x + threadIdx.x;
    if (e < NE) rank[e] = atomicAdd(&counts[ei[NE + e]], 1);
}

__global__ void k_s1(const int* __restrict__ counts, int* __restrict__ bsum) {
    __shared__ int sd[256];
    int tid = threadIdx.x, b = blockIdx.x;
    int base = b * 2048 + tid * 8;
    int s = 0;
    #pragma unroll
    for (int j = 0; j < 8; ++j) {
        int g = base + j;
        s += (g < NN) ? counts[g] : 0;
    }
    sd[tid] = s;
    __syncthreads();
    for (int d = 128; d; d >>= 1) {
        if (tid < d) sd[tid] += sd[tid + d];
        __syncthreads();
    }
    if (tid == 0) bsum[b] = sd[0];
}

__global__ void k_s2(const int* __restrict__ bsum, int* __restrict__ boff,
                     int* __restrict__ rowptr,
                     const float* __restrict__ We1, const float* __restrict__ ae1,
                     const float* __restrict__ We2, const float* __restrict__ ae2,
                     float* __restrict__ wdot) {
    int t = threadIdx.x;
    if (t == 0) {
        int run = 0;
        for (int b = 0; b < 49; ++b) { boff[b] = run; run += bsum[b]; }
        rowptr[NN] = NE;
    }
    if (t >= 64 && t < 68) {
        int h = t - 64;
        float s = 0.f;
        for (int c = 0; c < 32; ++c) s += We1[h*32+c] * ae1[h*32+c];
        wdot[h] = s;
    } else if (t == 68) {
        float s = 0.f;
        for (int c = 0; c < 32; ++c) s += We2[c] * ae2[c];
        wdot[4] = s;
    }
}

__global__ void k_s3(const int* __restrict__ counts, const int* __restrict__ boff,
                     int* __restrict__ rowptr) {
    __shared__ int sT[256];
    int tid = threadIdx.x, b = blockIdx.x;
    int base = b * 2048 + tid * 8;
    int c[8];
    int s = 0;
    #pragma unroll
    for (int j = 0; j < 8; ++j) {
        int g = base + j;
        c[j] = (g < NN) ? counts[g] : 0;
        s += c[j];
    }
    sT[tid] = s;
    __syncthreads();
    for (int d = 1; d < 256; d <<= 1) {
        int v = (tid >= d) ? sT[tid - d] : 0;
        __syncthreads();
        sT[tid] += v;
        __syncthreads();
    }
    int run = (tid ? sT[tid - 1] : 0) + boff[b];
    #pragma unroll
    for (int j = 0; j < 8; ++j) {
        int g = base + j;
        if (g < NN) rowptr[g] = run;
        run += c[j];
    }
}

// ---------- node transform L1: h1 fp16, alpha_src/dst ----------
__global__ void __launch_bounds__(256, 2)
k1_node1(const float* __restrict__ x, const float* __restrict__ W1,
         const float* __restrict__ as1, const float* __restrict__ ad1,
         __half2* __restrict__ h1h, float* __restrict__ as1n,
         float* __restrict__ ad1n) {
    int tid = threadIdx.x, wid = tid >> 6, lane = tid & 63;
    float wc0[64], wc1[64];
    #pragma unroll
    for (int k = 0; k < 64; ++k) {
        wc0[k] = W1[k*128 + 2*lane];
        wc1[k] = W1[k*128 + 2*lane + 1];
    }
    float asc0 = as1[2*lane], asc1 = as1[2*lane+1];
    float adc0 = ad1[2*lane], adc1 = ad1[2*lane+1];
    int gw = (blockIdx.x << 2) + wid;
    int nw = gridDim.x << 2;
    for (int n = gw; n < NN; n += nw) {
        int nu = __builtin_amdgcn_readfirstlane(n);
        const float* xr = x + (size_t)nu * 64;
        float a0 = 0.f, a1 = 0.f;
        #pragma unroll
        for (int k = 0; k < 64; ++k) {
            float xk = xr[k];
            a0 = fmaf(xk, wc0[k], a0);
            a1 = fmaf(xk, wc1[k], a1);
        }
        h1h[(size_t)nu*64 + lane] = __float22half2_rn(make_float2(a0, a1));
        float p = a0*asc0 + a1*asc1;
        float q = a0*adc0 + a1*adc1;
        #pragma unroll
        for (int d = 1; d < 16; d <<= 1) {
            p += __shfl_xor(p, d);
            q += __shfl_xor(q, d);
        }
        if ((lane & 15) == 0) {
            int h = lane >> 4;
            as1n[nu*4 + h] = p;
            ad1n[nu*4 + h] = q;
        }
    }
}

// ---------- scatter + L1 exp precompute: ONE int4 record per edge ----------
__global__ void k_scatter(const int* __restrict__ ei, const float* __restrict__ ea,
                          const float* __restrict__ g, const float* __restrict__ b,
                          const float* __restrict__ m, const float* __restrict__ v,
                          const int* __restrict__ rowptr, const int* __restrict__ rank,
                          const float* __restrict__ as1n, const float* __restrict__ ad1n,
                          const float* __restrict__ wdot, int4* __restrict__ rec) {
    int e = blockIdx.x * blockDim.x + threadIdx.x;
    if (e >= NE) return;
    int src = ei[e], dst = ei[NE + e];
    int pos = rowptr[dst] + rank[e];
    float en = (log1pf(ea[e]) - m[0]) * rsqrtf(v[0] + 1e-5f) * g[0] + b[0];
    float4 wd  = *(const float4*)wdot;
    float4 asv = *(const float4*)&as1n[src*4];
    float4 adv = *(const float4*)&ad1n[dst*4];
    float a0 = asv.x + adv.x + en*wd.x; a0 = fmaxf(a0, 0.2f*a0);
    float a1 = asv.y + adv.y + en*wd.y; a1 = fmaxf(a1, 0.2f*a1);
    float a2 = asv.z + adv.z + en*wd.z; a2 = fmaxf(a2, 0.2f*a2);
    float a3 = asv.w + adv.w + en*wd.w; a3 = fmaxf(a3, 0.2f*a3);
    __half2 p01 = __floats2half2_rn(__expf(a0), __expf(a1));
    __half2 p23 = __floats2half2_rn(__expf(a2), __expf(a3));
    int4 rc;
    rc.x = src;
    rc.y = __float_as_int(en);
    rc.z = *(const int*)&p01;
    rc.w = *(const int*)&p23;
    rec[pos] = rc;
}

// ---------- L1 aggregate: 16 nodes/block, 4/wave; mix-fma inner ----------
__global__ void __launch_bounds__(256)
kA1(const int* __restrict__ rowptr, const int4* __restrict__ rec,
    const __half2* __restrict__ h1h,
    const float* __restrict__ b1, const float* __restrict__ W2,
    const float* __restrict__ as2, const float* __restrict__ ad2,
    __half2* __restrict__ h2h, float* __restrict__ as2n, float* __restrict__ ad2n) {
    __shared__ __half2 W2h[64*32];          // (k-pair, col): 8KB
    __shared__ float4 exs4[4][64];
    __shared__ int    srcl[4][64];
    __shared__ float  slot[4][128];
    int tid = threadIdx.x, wid = tid >> 6, lane = tid & 63;
    for (int i = tid; i < 2048; i += 256) {
        int k2 = i >> 5, c = i & 31;
        W2h[i] = __floats2half2_rn(W2[(2*k2)*32 + c], W2[(2*k2+1)*32 + c]);
    }
    __syncthreads();

    int es4 = lane >> 4;         // edge slot (0..3)
    int co  = lane & 15;         // channel oct: channels 8co..8co+7
    int hq4 = co >> 2;           // head of these channels
    int es = lane >> 5, cq = lane & 31;
    int l4 = lane & 15;
    const float* exf = (const float*)&exs4[wid][0];
    const uint4* h1u4 = (const uint4*)h1h;

    for (int nn = 0; nn < 4; ++nn) {
        int n = blockIdx.x * 16 + wid * 4 + nn;
        int row0 = rowptr[n], row1 = rowptr[n + 1];
        float den0 = 0.f, den1 = 0.f, den2 = 0.f, den3 = 0.f;
        float acc[8] = {0.f,0.f,0.f,0.f,0.f,0.f,0.f,0.f};

        for (int base = row0; base < row1; base += 64) {
            int j = base + lane;
            bool val = j < row1;
            int4 rc = val ? rec[j] : make_int4(0, 0, 0, 0);
            float2 e01 = __half22float2(*(const __half2*)&rc.z);
            float2 e23 = __half22float2(*(const __half2*)&rc.w);
            den0 += e01.x; den1 += e01.y; den2 += e23.x; den3 += e23.y;
            exs4[wid][lane] = make_float4(e01.x, e01.y, e23.x, e23.y);
            srcl[wid][lane] = rc.x;
            // same-wave LDS: in-order, no barrier

            int cnt = min(64, row1 - base);
            #pragma unroll 2
            for (int i = 0; i < cnt; i += 4) {
                int idx = i + es4;
                bool ok = idx < cnt;
                int s = srcl[wid][ok ? idx : i];
                float ex = ok ? exf[idx*4 + hq4] : 0.f;
                union { uint4 u; __half h[8]; } u;
                u.u = h1u4[(size_t)s*16 + co];        // 8 channels, 16B
                #pragma unroll
                for (int k = 0; k < 8; ++k)
                    acc[k] = fmaf(ex, __half2float(u.h[k]), acc[k]);  // v_fma_mix
            }
        }
        // merge 4 edge-slot partials; reduce denominators wave-wide
        #pragma unroll
        for (int k = 0; k < 8; ++k) {
            acc[k] += __shfl_xor(acc[k], 16);
            acc[k] += __shfl_xor(acc[k], 32);
        }
        #pragma unroll
        for (int d = 32; d; d >>= 1) {
            den0 += __shfl_xor(den0, d); den1 += __shfl_xor(den1, d);
            den2 += __shfl_xor(den2, d); den3 += __shfl_xor(den3, d);
        }
        float dh = (hq4 == 0) ? den0 : (hq4 == 1) ? den1 : (hq4 == 2) ? den2 : den3;
        float r = 1.f / (dh + 1e-16f);
        if (es4 == 0) {
            float4 blo = ((const float4*)b1)[2*co];
            float4 bhi = ((const float4*)b1)[2*co + 1];
            float o0 = acc[0]*r + blo.x; o0 = o0 > 0.f ? o0 : expm1f(o0);
            float o1 = acc[1]*r + blo.y; o1 = o1 > 0.f ? o1 : expm1f(o1);
            float o2 = acc[2]*r + blo.z; o2 = o2 > 0.f ? o2 : expm1f(o2);
            float o3 = acc[3]*r + blo.w; o3 = o3 > 0.f ? o3 : expm1f(o3);
            float o4 = acc[4]*r + bhi.x; o4 = o4 > 0.f ? o4 : expm1f(o4);
            float o5 = acc[5]*r + bhi.y; o5 = o5 > 0.f ? o5 : expm1f(o5);
            float o6 = acc[6]*r + bhi.z; o6 = o6 > 0.f ? o6 : expm1f(o6);
            float o7 = acc[7]*r + bhi.w; o7 = o7 > 0.f ? o7 : expm1f(o7);
            *(float4*)&slot[wid][8*co]     = make_float4(o0, o1, o2, o3);
            *(float4*)&slot[wid][8*co + 4] = make_float4(o4, o5, o6, o7);
        }
        // same-wave LDS: in-order, no barrier

        // h2 = elu(out1) @ W2, k-split across wave halves
        int k2base = es * 32;
        float s2 = 0.f;
        #pragma unroll
        for (int kk = 0; kk < 32; ++kk) {
            __half2 w = W2h[(k2base + kk)*32 + cq];
            s2 = fmaf(slot[wid][2*(k2base + kk)],
                      __half2float(__low2half(w)), s2);     // v_fma_mix
            s2 = fmaf(slot[wid][2*(k2base + kk) + 1],
                      __half2float(__high2half(w)), s2);
        }
        s2 += __shfl_xor(s2, 32);
        float za = __shfl(s2, 2*l4);
        float zb = __shfl(s2, 2*l4 + 1);
        if (lane < 16) h2h[(size_t)n*16 + l4] = __float22half2_rn(make_float2(za, zb));
        float av = s2 * as2[cq] * 0.5f;
        float dv = s2 * ad2[cq] * 0.5f;
        #pragma unroll
        for (int d = 32; d; d >>= 1) { av += __shfl_xor(av, d); dv += __shfl_xor(dv, d); }
        if (lane == 0) { as2n[n] = av; ad2n[n] = dv; }
    }
}

// ---------- L2 aggregate: 16 nodes/block; 8 edges/iter; mix-fma + decoder ----------
__global__ void __launch_bounds__(256)
kA2(const int* __restrict__ rowptr, const int4* __restrict__ rec,
    const float* __restrict__ as2n, const float* __restrict__ ad2n,
    const float* __restrict__ wdot, const __half2* __restrict__ h2h,
    const float* __restrict__ b2, const float* __restrict__ Wd1,
    const float* __restrict__ bd1, const float* __restrict__ Wd2,
    const float* __restrict__ bd2, float* __restrict__ out) {
    __shared__ float Wd1s[32*32], Wd2s[32*64];
    __shared__ float pl[4][64];
    __shared__ int   srcl[4][64];
    __shared__ float zs[4][32], ts[4][32];
    int tid = threadIdx.x, wid = tid >> 6, lane = tid & 63;
    int es8 = lane >> 3, l3 = lane & 7;    // edge slot (0..7), channel quad 4*l3..
    int half = lane >> 5, l5 = lane & 31;
    for (int i = tid; i < 1024; i += 256) Wd1s[i] = Wd1[i];
    for (int i = tid; i < 2048; i += 256) Wd2s[i] = Wd2[i];
    __syncthreads();

    float wd4 = wdot[4];
    const uint2* h2u2 = (const uint2*)h2h;

    for (int nn = 0; nn < 4; ++nn) {
        int n = blockIdx.x * 16 + wid * 4 + nn;
        int row0 = rowptr[n], row1 = rowptr[n + 1];
        float adn = ad2n[n];
        float den = 0.f;
        float acc[4] = {0.f, 0.f, 0.f, 0.f};

        for (int base = row0; base < row1; base += 64) {
            int j = base + lane;
            bool val = j < row1;
            int4 rc = val ? rec[j] : make_int4(0, 0, 0, 0);
            int sv = rc.x;
            float en = __int_as_float(rc.y);
            float a = as2n[sv] + adn + en * wd4;   // as2n: 400KB, L2-resident
            a = fmaxf(a, 0.2f*a);
            float p = val ? __expf(a) : 0.f;
            den += p;
            pl[wid][lane] = p;
            srcl[wid][lane] = sv;

            int cnt = min(64, row1 - base);
            #pragma unroll 2
            for (int i = 0; i < cnt; i += 8) {
                int idx = i + es8;
                bool ok = idx < cnt;
                int se   = ok ? srcl[wid][idx] : srcl[wid][i];
                float ex = ok ? pl[wid][idx] : 0.f;
                union { uint2 u; __half h[4]; } u;
                u.u = h2u2[(size_t)se*8 + l3];     // 4 channels, 8B
                #pragma unroll
                for (int k = 0; k < 4; ++k)
                    acc[k] = fmaf(ex, __half2float(u.h[k]), acc[k]);  // v_fma_mix
            }
        }
        #pragma unroll
        for (int d = 32; d; d >>= 1) den += __shfl_xor(den, d);
        #pragma unroll
        for (int k = 0; k < 4; ++k) {
            acc[k] += __shfl_xor(acc[k], 8);
            acc[k] += __shfl_xor(acc[k], 16);
            acc[k] += __shfl_xor(acc[k], 32);
        }
        float r = 1.f / (den + 1e-16f);
        if (lane < 8) {
            float4 b2v = ((const float4*)b2)[l3];
            float z0 = acc[0]*r + b2v.x;
            float z1 = acc[1]*r + b2v.y;
            float z2 = acc[2]*r + b2v.z;
            float z3 = acc[3]*r + b2v.w;
            *(float4*)&out[(size_t)n*32 + 4*l3] = make_float4(z0, z1, z2, z3);
            *(float4*)&zs[wid][4*l3] = make_float4(z0, z1, z2, z3);
        }
        // same-wave LDS: in-order, no barrier
        int kk0 = half * 16;
        float t2 = 0.f;
        #pragma unroll
        for (int k = 0; k < 16; ++k)
            t2 = fmaf(zs[wid][kk0 + k], Wd1s[(kk0 + k)*32 + l5], t2);
        t2 += __shfl_xor(t2, 32);
        t2 += bd1[l5];
        t2 = t2 > 0.f ? t2 : expm1f(t2);
        if (lane < 32) ts[wid][l5] = t2;

        float xo = bd2[lane];
        #pragma unroll
        for (int k = 0; k < 32; ++k)
            xo = fmaf(ts[wid][k], Wd2s[k*64 + lane], xo);
        out[(size_t)NN*32 + (size_t)n*64 + lane] = xo;
    }
}

extern "C" void kernel_launch(void* const* d_in, const int* in_sizes, int n_in,
                              void* d_out, int out_size, void* d_ws, size_t ws_size,
                              hipStream_t stream) {
    const float* x    = (const float*)d_in[0];
    const int*   ei   = (const int*)  d_in[1];
    const float* ea   = (const float*)d_in[2];
    const float* bng  = (const float*)d_in[3];
    const float* bnb  = (const float*)d_in[4];
    const float* bnm  = (const float*)d_in[5];
    const float* bnv  = (const float*)d_in[6];
    const float* W1   = (const float*)d_in[7];
    const float* as1  = (const float*)d_in[8];
    const float* ad1  = (const float*)d_in[9];
    const float* We1  = (const float*)d_in[10];
    const float* ae1  = (const float*)d_in[11];
    const float* b1   = (const float*)d_in[12];
    const float* W2   = (const float*)d_in[13];
    const float* as2  = (const float*)d_in[14];
    const float* ad2  = (const float*)d_in[15];
    const float* We2  = (const float*)d_in[16];
    const float* ae2  = (const float*)d_in[17];
    const float* b2   = (const float*)d_in[18];
    const float* Wd1  = (const float*)d_in[19];
    const float* bd1  = (const float*)d_in[20];
    const float* Wd2  = (const float*)d_in[21];
    const float* bd2  = (const float*)d_in[22];
    float* out = (float*)d_out;

    char* wsb = (char*)d_ws;
    __half2* h1h = (__half2*)wsb;                          // NN*64*4B = 25.6MB
    float* as1n  = (float*)(wsb += (size_t)NN*64*4);       // NN*4
    float* ad1n  = (float*)(wsb += (size_t)NN*4*4);        // NN*4
    __half2* h2h = (__half2*)(wsb += (size_t)NN*4*4);      // NN*16*4B
    float* as2n  = (float*)(wsb += (size_t)NN*16*4);       // NN
    float* ad2n  = (float*)(wsb += (size_t)NN*4);          // NN
    float* wdot  = (float*)(wsb += (size_t)NN*4);          // 8
    int4* rec    = (int4*)(wsb += 8*4);                    // NE*16B
    int* rank    = (int*)(wsb += (size_t)NE*16);           // NE
    int* counts  = (int*)(wsb += (size_t)NE*4);            // NN
    int* rowptr  = (int*)(wsb += (size_t)NN*4);            // NN+1
    int* bsum    = (int*)(wsb += (size_t)(NN+1)*4);        // 64
    int* boff    = (int*)(wsb += 64*4);                    // 64

    hipMemsetAsync(counts, 0, NN * sizeof(int), stream);
    hipLaunchKernelGGL(k_hist, dim3((NE+255)/256), dim3(256), 0, stream, ei, counts, rank);
    hipLaunchKernelGGL(k_s1, dim3(49), dim3(256), 0, stream, counts, bsum);
    hipLaunchKernelGGL(k_s2, dim3(1), dim3(128), 0, stream,
                       bsum, boff, rowptr, We1, ae1, We2, ae2, wdot);
    hipLaunchKernelGGL(k_s3, dim3(49), dim3(256), 0, stream, counts, boff, rowptr);
    hipLaunchKernelGGL(k1_node1, dim3(1024), dim3(256), 0, stream,
                       x, W1, as1, ad1, h1h, as1n, ad1n);
    hipLaunchKernelGGL(k_scatter, dim3((NE+255)/256), dim3(256), 0, stream,
                       ei, ea, bng, bnb, bnm, bnv, rowptr, rank,
                       as1n, ad1n, wdot, rec);
    hipLaunchKernelGGL(kA1, dim3(NN/16), dim3(256), 0, stream,
                       rowptr, rec, h1h, b1, W2, as2, ad2, h2h, as2n, ad2n);
    hipLaunchKernelGGL(kA2, dim3(NN/16), dim3(256), 0, stream,
                       rowptr, rec, as2n, ad2n, wdot, h2h, b2, Wd1, bd1, Wd2, bd2,
                       out);
}

// Round 12
// 398.016 us; speedup vs baseline: 1.1028x; 1.1028x over previous
//
#include <hip/hip_runtime.h>
#include <hip/hip_fp16.h>
#include <math.h>

#define NN 100000
#define NE 1600000

// ---------- CSR build: hist with rank recording ----------
__global__ void k_hist(const int* __restrict__ ei, int* __restrict__ counts,
                       int* __restrict__ rank) {
    int e = blockIdx.x * blockDim.x + threadIdx.x;
    if (e < NE) rank[e] = atomicAdd(&counts[ei[NE + e]], 1);
}

__global__ void k_s1(const int* __restrict__ counts, int* __restrict__ bsum) {
    __shared__ int sd[256];
    int tid = threadIdx.x, b = blockIdx.x;
    int base = b * 2048 + tid * 8;
    int s = 0;
    #pragma unroll
    for (int j = 0; j < 8; ++j) {
        int g = base + j;
        s += (g < NN) ? counts[g] : 0;
    }
    sd[tid] = s;
    __syncthreads();
    for (int d = 128; d; d >>= 1) {
        if (tid < d) sd[tid] += sd[tid + d];
        __syncthreads();
    }
    if (tid == 0) bsum[b] = sd[0];
}

__global__ void k_s2(const int* __restrict__ bsum, int* __restrict__ boff,
                     int* __restrict__ rowptr,
                     const float* __restrict__ We1, const float* __restrict__ ae1,
                     const float* __restrict__ We2, const float* __restrict__ ae2,
                     float* __restrict__ wdot) {
    int t = threadIdx.x;
    if (t == 0) {
        int run = 0;
        for (int b = 0; b < 49; ++b) { boff[b] = run; run += bsum[b]; }
        rowptr[NN] = NE;
    }
    if (t >= 64 && t < 68) {
        int h = t - 64;
        float s = 0.f;
        for (int c = 0; c < 32; ++c) s += We1[h*32+c] * ae1[h*32+c];
        wdot[h] = s;
    } else if (t == 68) {
        float s = 0.f;
        for (int c = 0; c < 32; ++c) s += We2[c] * ae2[c];
        wdot[4] = s;
    }
}

__global__ void k_s3(const int* __restrict__ counts, const int* __restrict__ boff,
                     int* __restrict__ rowptr) {
    __shared__ int sT[256];
    int tid = threadIdx.x, b = blockIdx.x;
    int base = b * 2048 + tid * 8;
    int c[8];
    int s = 0;
    #pragma unroll
    for (int j = 0; j < 8; ++j) {
        int g = base + j;
        c[j] = (g < NN) ? counts[g] : 0;
        s += c[j];
    }
    sT[tid] = s;
    __syncthreads();
    for (int d = 1; d < 256; d <<= 1) {
        int v = (tid >= d) ? sT[tid - d] : 0;
        __syncthreads();
        sT[tid] += v;
        __syncthreads();
    }
    int run = (tid ? sT[tid - 1] : 0) + boff[b];
    #pragma unroll
    for (int j = 0; j < 8; ++j) {
        int g = base + j;
        if (g < NN) rowptr[g] = run;
        run += c[j];
    }
}

// ---------- node transform L1: h1 fp16, alpha_src/dst ----------
__global__ void __launch_bounds__(256, 2)
k1_node1(const float* __restrict__ x, const float* __restrict__ W1,
         const float* __restrict__ as1, const float* __restrict__ ad1,
         __half2* __restrict__ h1h, float* __restrict__ as1n,
         float* __restrict__ ad1n) {
    int tid = threadIdx.x, wid = tid >> 6, lane = tid & 63;
    float wc0[64], wc1[64];
    #pragma unroll
    for (int k = 0; k < 64; ++k) {
        wc0[k] = W1[k*128 + 2*lane];
        wc1[k] = W1[k*128 + 2*lane + 1];
    }
    float asc0 = as1[2*lane], asc1 = as1[2*lane+1];
    float adc0 = ad1[2*lane], adc1 = ad1[2*lane+1];
    int gw = (blockIdx.x << 2) + wid;
    int nw = gridDim.x << 2;
    for (int n = gw; n < NN; n += nw) {
        int nu = __builtin_amdgcn_readfirstlane(n);
        const float* xr = x + (size_t)nu * 64;
        float a0 = 0.f, a1 = 0.f;
        #pragma unroll
        for (int k = 0; k < 64; ++k) {
            float xk = xr[k];
            a0 = fmaf(xk, wc0[k], a0);
            a1 = fmaf(xk, wc1[k], a1);
        }
        h1h[(size_t)nu*64 + lane] = __float22half2_rn(make_float2(a0, a1));
        float p = a0*asc0 + a1*asc1;
        float q = a0*adc0 + a1*adc1;
        #pragma unroll
        for (int d = 1; d < 16; d <<= 1) {
            p += __shfl_xor(p, d);
            q += __shfl_xor(q, d);
        }
        if ((lane & 15) == 0) {
            int h = lane >> 4;
            as1n[nu*4 + h] = p;
            ad1n[nu*4 + h] = q;
        }
    }
}

// ---------- scatter + L1 exp precompute: ONE int4 record per edge ----------
__global__ void k_scatter(const int* __restrict__ ei, const float* __restrict__ ea,
                          const float* __restrict__ g, const float* __restrict__ b,
                          const float* __restrict__ m, const float* __restrict__ v,
                          const int* __restrict__ rowptr, const int* __restrict__ rank,
                          const float* __restrict__ as1n, const float* __restrict__ ad1n,
                          const float* __restrict__ wdot, int4* __restrict__ rec) {
    int e = blockIdx.x * blockDim.x + threadIdx.x;
    if (e >= NE) return;
    int src = ei[e], dst = ei[NE + e];
    int pos = rowptr[dst] + rank[e];
    float en = (log1pf(ea[e]) - m[0]) * rsqrtf(v[0] + 1e-5f) * g[0] + b[0];
    float4 wd  = *(const float4*)wdot;
    float4 asv = *(const float4*)&as1n[src*4];
    float4 adv = *(const float4*)&ad1n[dst*4];
    float a0 = asv.x + adv.x + en*wd.x; a0 = fmaxf(a0, 0.2f*a0);
    float a1 = asv.y + adv.y + en*wd.y; a1 = fmaxf(a1, 0.2f*a1);
    float a2 = asv.z + adv.z + en*wd.z; a2 = fmaxf(a2, 0.2f*a2);
    float a3 = asv.w + adv.w + en*wd.w; a3 = fmaxf(a3, 0.2f*a3);
    __half2 p01 = __floats2half2_rn(__expf(a0), __expf(a1));
    __half2 p23 = __floats2half2_rn(__expf(a2), __expf(a3));
    int4 rc;
    rc.x = src;
    rc.y = __float_as_int(en);
    rc.z = *(const int*)&p01;
    rc.w = *(const int*)&p23;
    rec[pos] = rc;
}

// ---------- L1 aggregate: 4 edges/iter, 16 lanes/edge, mix-fma, no guards ----------
__global__ void __launch_bounds__(256)
kA1(const int* __restrict__ rowptr, const int4* __restrict__ rec,
    const __half2* __restrict__ h1h,
    const float* __restrict__ b1, const float* __restrict__ W2,
    const float* __restrict__ as2, const float* __restrict__ ad2,
    __half2* __restrict__ h2h, float* __restrict__ as2n, float* __restrict__ ad2n) {
    __shared__ __half2 W2h[64*32];          // (k-pair, col): 8KB
    __shared__ float4 exs4[4][64];
    __shared__ int    srcl[4][64];
    __shared__ float  slot[4][128];
    int tid = threadIdx.x, wid = tid >> 6, lane = tid & 63;
    for (int i = tid; i < 2048; i += 256) {
        int k2 = i >> 5, c = i & 31;
        W2h[i] = __floats2half2_rn(W2[(2*k2)*32 + c], W2[(2*k2+1)*32 + c]);
    }
    __syncthreads();

    int n = blockIdx.x * 4 + wid;
    int row0 = rowptr[n], row1 = rowptr[n + 1];
    int es4 = lane >> 4;         // edge slot (0..3)
    int co  = lane & 15;         // channel oct: channels 8co..8co+7
    int hq4 = co >> 2;           // head of these channels
    float den0 = 0.f, den1 = 0.f, den2 = 0.f, den3 = 0.f;
    float acc[8] = {0.f,0.f,0.f,0.f,0.f,0.f,0.f,0.f};
    const float* exf = (const float*)&exs4[wid][0];
    const uint4* h1u4 = (const uint4*)h1h;

    for (int base = row0; base < row1; base += 64) {
        int j = base + lane;
        bool val = j < row1;
        int4 rc = val ? rec[j] : make_int4(0, 0, 0, 0);
        float2 e01 = __half22float2(*(const __half2*)&rc.z);
        float2 e23 = __half22float2(*(const __half2*)&rc.w);
        den0 += e01.x; den1 += e01.y; den2 += e23.x; den3 += e23.y;
        exs4[wid][lane] = make_float4(e01.x, e01.y, e23.x, e23.y);
        srcl[wid][lane] = rc.x;
        // same-wave LDS: in-order, no barrier.
        // invalid lanes stored ex=0 (rc=0 -> half 0.0) and src=0: inner loop
        // needs NO validity guards - zero weight annihilates garbage h1 rows.

        int cnt = min(64, row1 - base);
        for (int i = 0; i < cnt; i += 4) {
            int idx = i + es4;                         // may exceed cnt: ex=0 there
            int s = srcl[wid][idx];
            float ex = exf[idx*4 + hq4];
            uint4 u = h1u4[(size_t)s*16 + co];         // 8 channels, 16B
            __half2 h01 = *(const __half2*)&u.x;
            __half2 h23 = *(const __half2*)&u.y;
            __half2 h45 = *(const __half2*)&u.z;
            __half2 h67 = *(const __half2*)&u.w;
            acc[0] = fmaf(ex, __half2float(__low2half(h01)),  acc[0]);
            acc[1] = fmaf(ex, __half2float(__high2half(h01)), acc[1]);
            acc[2] = fmaf(ex, __half2float(__low2half(h23)),  acc[2]);
            acc[3] = fmaf(ex, __half2float(__high2half(h23)), acc[3]);
            acc[4] = fmaf(ex, __half2float(__low2half(h45)),  acc[4]);
            acc[5] = fmaf(ex, __half2float(__high2half(h45)), acc[5]);
            acc[6] = fmaf(ex, __half2float(__low2half(h67)),  acc[6]);
            acc[7] = fmaf(ex, __half2float(__high2half(h67)), acc[7]);
        }
    }
    // merge 4 edge-slot partials; reduce denominators wave-wide
    #pragma unroll
    for (int k = 0; k < 8; ++k) {
        acc[k] += __shfl_xor(acc[k], 16);
        acc[k] += __shfl_xor(acc[k], 32);
    }
    #pragma unroll
    for (int d = 32; d; d >>= 1) {
        den0 += __shfl_xor(den0, d); den1 += __shfl_xor(den1, d);
        den2 += __shfl_xor(den2, d); den3 += __shfl_xor(den3, d);
    }
    float dh = (hq4 == 0) ? den0 : (hq4 == 1) ? den1 : (hq4 == 2) ? den2 : den3;
    float r = 1.f / (dh + 1e-16f);
    if (es4 == 0) {
        float4 blo = ((const float4*)b1)[2*co];
        float4 bhi = ((const float4*)b1)[2*co + 1];
        float o0 = acc[0]*r + blo.x; o0 = o0 > 0.f ? o0 : expm1f(o0);
        float o1 = acc[1]*r + blo.y; o1 = o1 > 0.f ? o1 : expm1f(o1);
        float o2 = acc[2]*r + blo.z; o2 = o2 > 0.f ? o2 : expm1f(o2);
        float o3 = acc[3]*r + blo.w; o3 = o3 > 0.f ? o3 : expm1f(o3);
        float o4 = acc[4]*r + bhi.x; o4 = o4 > 0.f ? o4 : expm1f(o4);
        float o5 = acc[5]*r + bhi.y; o5 = o5 > 0.f ? o5 : expm1f(o5);
        float o6 = acc[6]*r + bhi.z; o6 = o6 > 0.f ? o6 : expm1f(o6);
        float o7 = acc[7]*r + bhi.w; o7 = o7 > 0.f ? o7 : expm1f(o7);
        *(float4*)&slot[wid][8*co]     = make_float4(o0, o1, o2, o3);
        *(float4*)&slot[wid][8*co + 4] = make_float4(o4, o5, o6, o7);
    }
    // same-wave LDS: in-order, no barrier

    // h2 = elu(out1) @ W2, k-split across wave halves
    int es = lane >> 5, cq = lane & 31;
    int k2base = es * 32;
    float s2 = 0.f;
    #pragma unroll
    for (int kk = 0; kk < 32; ++kk) {
        __half2 w = W2h[(k2base + kk)*32 + cq];
        s2 = fmaf(slot[wid][2*(k2base + kk)],     __half2float(__low2half(w)),  s2);
        s2 = fmaf(slot[wid][2*(k2base + kk) + 1], __half2float(__high2half(w)), s2);
    }
    s2 += __shfl_xor(s2, 32);
    int l4 = lane & 15;
    float za = __shfl(s2, 2*l4);
    float zb = __shfl(s2, 2*l4 + 1);
    if (lane < 16) h2h[(size_t)n*16 + l4] = __float22half2_rn(make_float2(za, zb));
    float av = s2 * as2[cq] * 0.5f;
    float dv = s2 * ad2[cq] * 0.5f;
    #pragma unroll
    for (int d = 32; d; d >>= 1) { av += __shfl_xor(av, d); dv += __shfl_xor(dv, d); }
    if (lane == 0) { as2n[n] = av; ad2n[n] = dv; }
}

// ---------- L2 aggregate: 8 edges/iter, 8 lanes/edge, mix-fma + decoder ----------
__global__ void __launch_bounds__(256)
kA2(const int* __restrict__ rowptr, const int4* __restrict__ rec,
    const float* __restrict__ as2n, const float* __restrict__ ad2n,
    const float* __restrict__ wdot, const __half2* __restrict__ h2h,
    const float* __restrict__ b2, const float* __restrict__ Wd1,
    const float* __restrict__ bd1, const float* __restrict__ Wd2,
    const float* __restrict__ bd2, float* __restrict__ out) {
    __shared__ float Wd1s[32*32], Wd2s[32*64];
    __shared__ float pl[4][64];
    __shared__ int   srcl[4][64];
    __shared__ float zs[4][32], ts[4][32];
    int tid = threadIdx.x, wid = tid >> 6, lane = tid & 63;
    int es8 = lane >> 3, l3 = lane & 7;    // edge slot (0..7), channel quad 4*l3..
    int half = lane >> 5, l5 = lane & 31;
    for (int i = tid; i < 1024; i += 256) Wd1s[i] = Wd1[i];
    for (int i = tid; i < 2048; i += 256) Wd2s[i] = Wd2[i];
    __syncthreads();

    int n = blockIdx.x * 4 + wid;
    int row0 = rowptr[n], row1 = rowptr[n + 1];
    float wd4 = wdot[4];
    float adn = ad2n[n];
    float den = 0.f;
    float acc[4] = {0.f, 0.f, 0.f, 0.f};
    const uint2* h2u2 = (const uint2*)h2h;

    for (int base = row0; base < row1; base += 64) {
        int j = base + lane;
        bool val = j < row1;
        int4 rc = val ? rec[j] : make_int4(0, 0, 0, 0);
        int sv = rc.x;
        float en = __int_as_float(rc.y);
        float a = as2n[sv] + adn + en * wd4;   // as2n: 400KB, L2-resident
        a = fmaxf(a, 0.2f*a);
        float p = val ? __expf(a) : 0.f;
        den += p;
        pl[wid][lane] = p;
        srcl[wid][lane] = sv;
        // invalid lanes: p=0, src=0 -> no inner guards needed

        int cnt = min(64, row1 - base);
        for (int i = 0; i < cnt; i += 8) {
            int idx = i + es8;
            int se   = srcl[wid][idx];
            float ex = pl[wid][idx];
            uint2 u = h2u2[(size_t)se*8 + l3];     // 4 channels, 8B
            __half2 h01 = *(const __half2*)&u.x;
            __half2 h23 = *(const __half2*)&u.y;
            acc[0] = fmaf(ex, __half2float(__low2half(h01)),  acc[0]);
            acc[1] = fmaf(ex, __half2float(__high2half(h01)), acc[1]);
            acc[2] = fmaf(ex, __half2float(__low2half(h23)),  acc[2]);
            acc[3] = fmaf(ex, __half2float(__high2half(h23)), acc[3]);
        }
    }
    #pragma unroll
    for (int d = 32; d; d >>= 1) den += __shfl_xor(den, d);
    #pragma unroll
    for (int k = 0; k < 4; ++k) {
        acc[k] += __shfl_xor(acc[k], 8);
        acc[k] += __shfl_xor(acc[k], 16);
        acc[k] += __shfl_xor(acc[k], 32);
    }
    float r = 1.f / (den + 1e-16f);
    if (lane < 8) {
        float4 b2v = ((const float4*)b2)[l3];
        float z0 = acc[0]*r + b2v.x;
        float z1 = acc[1]*r + b2v.y;
        float z2 = acc[2]*r + b2v.z;
        float z3 = acc[3]*r + b2v.w;
        *(float4*)&out[(size_t)n*32 + 4*l3] = make_float4(z0, z1, z2, z3);
        *(float4*)&zs[wid][4*l3] = make_float4(z0, z1, z2, z3);
    }
    // same-wave LDS: in-order, no barrier
    int kk0 = half * 16;
    float t2 = 0.f;
    #pragma unroll
    for (int k = 0; k < 16; ++k)
        t2 = fmaf(zs[wid][kk0 + k], Wd1s[(kk0 + k)*32 + l5], t2);
    t2 += __shfl_xor(t2, 32);
    t2 += bd1[l5];
    t2 = t2 > 0.f ? t2 : expm1f(t2);
    if (lane < 32) ts[wid][l5] = t2;

    float xo = bd2[lane];
    #pragma unroll
    for (int k = 0; k < 32; ++k)
        xo = fmaf(ts[wid][k], Wd2s[k*64 + lane], xo);
    out[(size_t)NN*32 + (size_t)n*64 + lane] = xo;
}

extern "C" void kernel_launch(void* const* d_in, const int* in_sizes, int n_in,
                              void* d_out, int out_size, void* d_ws, size_t ws_size,
                              hipStream_t stream) {
    const float* x    = (const float*)d_in[0];
    const int*   ei   = (const int*)  d_in[1];
    const float* ea   = (const float*)d_in[2];
    const float* bng  = (const float*)d_in[3];
    const float* bnb  = (const float*)d_in[4];
    const float* bnm  = (const float*)d_in[5];
    const float* bnv  = (const float*)d_in[6];
    const float* W1   = (const float*)d_in[7];
    const float* as1  = (const float*)d_in[8];
    const float* ad1  = (const float*)d_in[9];
    const float* We1  = (const float*)d_in[10];
    const float* ae1  = (const float*)d_in[11];
    const float* b1   = (const float*)d_in[12];
    const float* W2   = (const float*)d_in[13];
    const float* as2  = (const float*)d_in[14];
    const float* ad2  = (const float*)d_in[15];
    const float* We2  = (const float*)d_in[16];
    const float* ae2  = (const float*)d_in[17];
    const float* b2   = (const float*)d_in[18];
    const float* Wd1  = (const float*)d_in[19];
    const float* bd1  = (const float*)d_in[20];
    const float* Wd2  = (const float*)d_in[21];
    const float* bd2  = (const float*)d_in[22];
    float* out = (float*)d_out;

    char* wsb = (char*)d_ws;
    __half2* h1h = (__half2*)wsb;                          // NN*64*4B = 25.6MB
    float* as1n  = (float*)(wsb += (size_t)NN*64*4);       // NN*4
    float* ad1n  = (float*)(wsb += (size_t)NN*4*4);        // NN*4
    __half2* h2h = (__half2*)(wsb += (size_t)NN*4*4);      // NN*16*4B
    float* as2n  = (float*)(wsb += (size_t)NN*16*4);       // NN
    float* ad2n  = (float*)(wsb += (size_t)NN*4);          // NN
    float* wdot  = (float*)(wsb += (size_t)NN*4);          // 8
    int4* rec    = (int4*)(wsb += 8*4);                    // NE*16B
    int* rank    = (int*)(wsb += (size_t)NE*16);           // NE
    int* counts  = (int*)(wsb += (size_t)NE*4);            // NN
    int* rowptr  = (int*)(wsb += (size_t)NN*4);            // NN+1
    int* bsum    = (int*)(wsb += (size_t)(NN+1)*4);        // 64
    int* boff    = (int*)(wsb += 64*4);                    // 64

    hipMemsetAsync(counts, 0, NN * sizeof(int), stream);
    hipLaunchKernelGGL(k_hist, dim3((NE+255)/256), dim3(256), 0, stream, ei, counts, rank);
    hipLaunchKernelGGL(k_s1, dim3(49), dim3(256), 0, stream, counts, bsum);
    hipLaunchKernelGGL(k_s2, dim3(1), dim3(128), 0, stream,
                       bsum, boff, rowptr, We1, ae1, We2, ae2, wdot);
    hipLaunchKernelGGL(k_s3, dim3(49), dim3(256), 0, stream, counts, boff, rowptr);
    hipLaunchKernelGGL(k1_node1, dim3(1024), dim3(256), 0, stream,
                       x, W1, as1, ad1, h1h, as1n, ad1n);
    hipLaunchKernelGGL(k_scatter, dim3((NE+255)/256), dim3(256), 0, stream,
                       ei, ea, bng, bnb, bnm, bnv, rowptr, rank,
                       as1n, ad1n, wdot, rec);
    hipLaunchKernelGGL(kA1, dim3(NN/4), dim3(256), 0, stream,
                       rowptr, rec, h1h, b1, W2, as2, ad2, h2h, as2n, ad2n);
    hipLaunchKernelGGL(kA2, dim3(NN/4), dim3(256), 0, stream,
                       rowptr, rec, as2n, ad2n, wdot, h2h, b2, Wd1, bd1, Wd2, bd2,
                       out);
}

// Round 13
// 379.490 us; speedup vs baseline: 1.1566x; 1.0488x over previous
//
#include <hip/hip_runtime.h>
#include <hip/hip_fp16.h>
#include <math.h>

#define NN 100000
#define NE 1600000

typedef _Float16 h2v __attribute__((ext_vector_type(2)));
__device__ __forceinline__ float fdot2f(__half2 a, __half2 b, float c) {
#if __has_builtin(__builtin_amdgcn_fdot2)
    return __builtin_amdgcn_fdot2(*(h2v*)&a, *(h2v*)&b, c, false);
#else
    c = fmaf(__half2float(__low2half(a)),  __half2float(__low2half(b)),  c);
    c = fmaf(__half2float(__high2half(a)), __half2float(__high2half(b)), c);
    return c;
#endif
}

// ---------- CSR build: hist with rank recording ----------
__global__ void k_hist(const int* __restrict__ ei, int* __restrict__ counts,
                       int* __restrict__ rank) {
    int e = blockIdx.x * blockDim.x + threadIdx.x;
    if (e < NE) rank[e] = atomicAdd(&counts[ei[NE + e]], 1);
}

__global__ void k_s1(const int* __restrict__ counts, int* __restrict__ bsum) {
    __shared__ int sd[256];
    int tid = threadIdx.x, b = blockIdx.x;
    int base = b * 2048 + tid * 8;
    int s = 0;
    #pragma unroll
    for (int j = 0; j < 8; ++j) {
        int g = base + j;
        s += (g < NN) ? counts[g] : 0;
    }
    sd[tid] = s;
    __syncthreads();
    for (int d = 128; d; d >>= 1) {
        if (tid < d) sd[tid] += sd[tid + d];
        __syncthreads();
    }
    if (tid == 0) bsum[b] = sd[0];
}

__global__ void k_s2(const int* __restrict__ bsum, int* __restrict__ boff,
                     int* __restrict__ rowptr,
                     const float* __restrict__ We1, const float* __restrict__ ae1,
                     const float* __restrict__ We2, const float* __restrict__ ae2,
                     float* __restrict__ wdot) {
    int t = threadIdx.x;
    if (t == 0) {
        int run = 0;
        for (int b = 0; b < 49; ++b) { boff[b] = run; run += bsum[b]; }
        rowptr[NN] = NE;
    }
    if (t >= 64 && t < 68) {
        int h = t - 64;
        float s = 0.f;
        for (int c = 0; c < 32; ++c) s += We1[h*32+c] * ae1[h*32+c];
        wdot[h] = s;
    } else if (t == 68) {
        float s = 0.f;
        for (int c = 0; c < 32; ++c) s += We2[c] * ae2[c];
        wdot[4] = s;
    }
}

__global__ void k_s3(const int* __restrict__ counts, const int* __restrict__ boff,
                     int* __restrict__ rowptr) {
    __shared__ int sT[256];
    int tid = threadIdx.x, b = blockIdx.x;
    int base = b * 2048 + tid * 8;
    int c[8];
    int s = 0;
    #pragma unroll
    for (int j = 0; j < 8; ++j) {
        int g = base + j;
        c[j] = (g < NN) ? counts[g] : 0;
        s += c[j];
    }
    sT[tid] = s;
    __syncthreads();
    for (int d = 1; d < 256; d <<= 1) {
        int v = (tid >= d) ? sT[tid - d] : 0;
        __syncthreads();
        sT[tid] += v;
        __syncthreads();
    }
    int run = (tid ? sT[tid - 1] : 0) + boff[b];
    #pragma unroll
    for (int j = 0; j < 8; ++j) {
        int g = base + j;
        if (g < NN) rowptr[g] = run;
        run += c[j];
    }
}

// ---------- node transform L1: h1 fp16, alpha_src/dst ----------
__global__ void __launch_bounds__(256, 2)
k1_node1(const float* __restrict__ x, const float* __restrict__ W1,
         const float* __restrict__ as1, const float* __restrict__ ad1,
         __half2* __restrict__ h1h, float* __restrict__ as1n,
         float* __restrict__ ad1n) {
    int tid = threadIdx.x, wid = tid >> 6, lane = tid & 63;
    float wc0[64], wc1[64];
    #pragma unroll
    for (int k = 0; k < 64; ++k) {
        wc0[k] = W1[k*128 + 2*lane];
        wc1[k] = W1[k*128 + 2*lane + 1];
    }
    float asc0 = as1[2*lane], asc1 = as1[2*lane+1];
    float adc0 = ad1[2*lane], adc1 = ad1[2*lane+1];
    int gw = (blockIdx.x << 2) + wid;
    int nw = gridDim.x << 2;
    for (int n = gw; n < NN; n += nw) {
        int nu = __builtin_amdgcn_readfirstlane(n);
        const float* xr = x + (size_t)nu * 64;
        float a0 = 0.f, a1 = 0.f;
        #pragma unroll
        for (int k = 0; k < 64; ++k) {
            float xk = xr[k];
            a0 = fmaf(xk, wc0[k], a0);
            a1 = fmaf(xk, wc1[k], a1);
        }
        h1h[(size_t)nu*64 + lane] = __float22half2_rn(make_float2(a0, a1));
        float p = a0*asc0 + a1*asc1;
        float q = a0*adc0 + a1*adc1;
        #pragma unroll
        for (int d = 1; d < 16; d <<= 1) {
            p += __shfl_xor(p, d);
            q += __shfl_xor(q, d);
        }
        if ((lane & 15) == 0) {
            int h = lane >> 4;
            as1n[nu*4 + h] = p;
            ad1n[nu*4 + h] = q;
        }
    }
}

// ---------- scatter + L1 exp precompute: ONE int4 record per edge ----------
__global__ void k_scatter(const int* __restrict__ ei, const float* __restrict__ ea,
                          const float* __restrict__ g, const float* __restrict__ b,
                          const float* __restrict__ m, const float* __restrict__ v,
                          const int* __restrict__ rowptr, const int* __restrict__ rank,
                          const float* __restrict__ as1n, const float* __restrict__ ad1n,
                          const float* __restrict__ wdot, int4* __restrict__ rec) {
    int e = blockIdx.x * blockDim.x + threadIdx.x;
    if (e >= NE) return;
    int src = ei[e], dst = ei[NE + e];
    int pos = rowptr[dst] + rank[e];
    float en = (log1pf(ea[e]) - m[0]) * rsqrtf(v[0] + 1e-5f) * g[0] + b[0];
    float4 wd  = *(const float4*)wdot;
    float4 asv = *(const float4*)&as1n[src*4];
    float4 adv = *(const float4*)&ad1n[dst*4];
    float a0 = asv.x + adv.x + en*wd.x; a0 = fmaxf(a0, 0.2f*a0);
    float a1 = asv.y + adv.y + en*wd.y; a1 = fmaxf(a1, 0.2f*a1);
    float a2 = asv.z + adv.z + en*wd.z; a2 = fmaxf(a2, 0.2f*a2);
    float a3 = asv.w + adv.w + en*wd.w; a3 = fmaxf(a3, 0.2f*a3);
    __half2 p01 = __floats2half2_rn(__expf(a0), __expf(a1));
    __half2 p23 = __floats2half2_rn(__expf(a2), __expf(a3));
    int4 rc;
    rc.x = src;
    rc.y = __float_as_int(en);
    rc.z = *(const int*)&p01;
    rc.w = *(const int*)&p23;
    rec[pos] = rc;
}

// ---------- L1 aggregate: all-lane epilogue, fdot2 W2, __expf ELU ----------
__global__ void __launch_bounds__(256)
kA1(const int* __restrict__ rowptr, const int4* __restrict__ rec,
    const __half2* __restrict__ h1h,
    const float* __restrict__ b1, const float* __restrict__ W2,
    const float* __restrict__ as2, const float* __restrict__ ad2,
    __half2* __restrict__ h2h, float* __restrict__ as2n, float* __restrict__ ad2n) {
    __shared__ __half2 W2h[64*32];          // (k-pair, col): 8KB
    __shared__ float4 exs4[4][64];
    __shared__ int    srcl[4][64];
    __shared__ __half2 slot_h2[4][64];      // out1 as 64 channel-pairs per node
    int tid = threadIdx.x, wid = tid >> 6, lane = tid & 63;
    for (int i = tid; i < 2048; i += 256) {
        int k2 = i >> 5, c = i & 31;
        W2h[i] = __floats2half2_rn(W2[(2*k2)*32 + c], W2[(2*k2+1)*32 + c]);
    }
    __syncthreads();

    int n = blockIdx.x * 4 + wid;
    int row0 = rowptr[n], row1 = rowptr[n + 1];
    int es4 = lane >> 4;         // edge slot (0..3)
    int co  = lane & 15;         // channel oct: channels 8co..8co+7
    int hq4 = co >> 2;           // head of these channels
    float den0 = 0.f, den1 = 0.f, den2 = 0.f, den3 = 0.f;
    float acc[8] = {0.f,0.f,0.f,0.f,0.f,0.f,0.f,0.f};
    const float* exf = (const float*)&exs4[wid][0];
    const uint4* h1u4 = (const uint4*)h1h;

    for (int base = row0; base < row1; base += 64) {
        int j = base + lane;
        bool val = j < row1;
        int4 rc = val ? rec[j] : make_int4(0, 0, 0, 0);
        float2 e01 = __half22float2(*(const __half2*)&rc.z);
        float2 e23 = __half22float2(*(const __half2*)&rc.w);
        den0 += e01.x; den1 += e01.y; den2 += e23.x; den3 += e23.y;
        exs4[wid][lane] = make_float4(e01.x, e01.y, e23.x, e23.y);
        srcl[wid][lane] = rc.x;
        // same-wave LDS: in-order, no barrier; invalid lanes store ex=0,src=0

        int cnt = min(64, row1 - base);
        for (int i = 0; i < cnt; i += 4) {
            int idx = i + es4;                         // may exceed cnt: ex=0 there
            int s = srcl[wid][idx];
            float ex = exf[idx*4 + hq4];
            uint4 u = h1u4[(size_t)s*16 + co];         // 8 channels, 16B
            __half2 h01 = *(const __half2*)&u.x;
            __half2 h23 = *(const __half2*)&u.y;
            __half2 h45 = *(const __half2*)&u.z;
            __half2 h67 = *(const __half2*)&u.w;
            acc[0] = fmaf(ex, __half2float(__low2half(h01)),  acc[0]);
            acc[1] = fmaf(ex, __half2float(__high2half(h01)), acc[1]);
            acc[2] = fmaf(ex, __half2float(__low2half(h23)),  acc[2]);
            acc[3] = fmaf(ex, __half2float(__high2half(h23)), acc[3]);
            acc[4] = fmaf(ex, __half2float(__low2half(h45)),  acc[4]);
            acc[5] = fmaf(ex, __half2float(__high2half(h45)), acc[5]);
            acc[6] = fmaf(ex, __half2float(__low2half(h67)),  acc[6]);
            acc[7] = fmaf(ex, __half2float(__high2half(h67)), acc[7]);
        }
    }
    // merge 4 edge-slot partials; reduce denominators wave-wide
    #pragma unroll
    for (int k = 0; k < 8; ++k) {
        acc[k] += __shfl_xor(acc[k], 16);
        acc[k] += __shfl_xor(acc[k], 32);
    }
    #pragma unroll
    for (int d = 32; d; d >>= 1) {
        den0 += __shfl_xor(den0, d); den1 += __shfl_xor(den1, d);
        den2 += __shfl_xor(den2, d); den3 += __shfl_xor(den3, d);
    }
    float dh = (hq4 == 0) ? den0 : (hq4 == 1) ? den1 : (hq4 == 2) ? den2 : den3;
    float r = 1.f / (dh + 1e-16f);
    // ALL lanes finalize 2 channels each: c0 = 8*co + 2*es4 (no masked ELU chains)
    float accA = (es4 == 0) ? acc[0] : (es4 == 1) ? acc[2] : (es4 == 2) ? acc[4] : acc[6];
    float accB = (es4 == 0) ? acc[1] : (es4 == 1) ? acc[3] : (es4 == 2) ? acc[5] : acc[7];
    int cp = 4*co + es4;                    // channel-pair index 0..63
    float2 bb = ((const float2*)b1)[cp];
    float oA = accA * r + bb.x;
    float oB = accB * r + bb.y;
    oA = oA > 0.f ? oA : __expf(oA) - 1.f;  // ELU via v_exp (not libm expm1f)
    oB = oB > 0.f ? oB : __expf(oB) - 1.f;
    slot_h2[wid][cp] = __floats2half2_rn(oA, oB);
    // same-wave LDS: in-order, no barrier

    // h2 = elu(out1) @ W2 via fdot2, k-split across wave halves
    int es = lane >> 5, cq = lane & 31;
    int k2base = es * 32;
    float s2 = 0.f;
    #pragma unroll
    for (int kk = 0; kk < 32; ++kk)
        s2 = fdot2f(slot_h2[wid][k2base + kk], W2h[(k2base + kk)*32 + cq], s2);
    s2 += __shfl_xor(s2, 32);
    int l4 = lane & 15;
    float za = __shfl(s2, 2*l4);
    float zb = __shfl(s2, 2*l4 + 1);
    if (lane < 16) h2h[(size_t)n*16 + l4] = __float22half2_rn(make_float2(za, zb));
    float av = s2 * as2[cq] * 0.5f;
    float dv = s2 * ad2[cq] * 0.5f;
    #pragma unroll
    for (int d = 32; d; d >>= 1) { av += __shfl_xor(av, d); dv += __shfl_xor(dv, d); }
    if (lane == 0) { as2n[n] = av; ad2n[n] = dv; }
}

// ---------- L2 aggregate: fdot2 decoder + __expf ELU ----------
__global__ void __launch_bounds__(256)
kA2(const int* __restrict__ rowptr, const int4* __restrict__ rec,
    const float* __restrict__ as2n, const float* __restrict__ ad2n,
    const float* __restrict__ wdot, const __half2* __restrict__ h2h,
    const float* __restrict__ b2, const float* __restrict__ Wd1,
    const float* __restrict__ bd1, const float* __restrict__ Wd2,
    const float* __restrict__ bd2, float* __restrict__ out) {
    __shared__ __half2 Wd1h[16*32];         // (k-pair, col): 2KB
    __shared__ __half2 Wd2h[16*64];         // (k-pair, col): 4KB
    __shared__ float pl[4][64];
    __shared__ int   srcl[4][64];
    __shared__ __half2 zh2[4][16], th2[4][16];
    int tid = threadIdx.x, wid = tid >> 6, lane = tid & 63;
    int es8 = lane >> 3, l3 = lane & 7;
    int half = lane >> 5, l5 = lane & 31;
    int l4 = lane & 15;
    for (int i = tid; i < 512; i += 256) {
        int kp = i >> 5, c = i & 31;
        Wd1h[i] = __floats2half2_rn(Wd1[(2*kp)*32 + c], Wd1[(2*kp+1)*32 + c]);
    }
    for (int i = tid; i < 1024; i += 256) {
        int kp = i >> 6, c = i & 63;
        Wd2h[i] = __floats2half2_rn(Wd2[(2*kp)*64 + c], Wd2[(2*kp+1)*64 + c]);
    }
    __syncthreads();

    int n = blockIdx.x * 4 + wid;
    int row0 = rowptr[n], row1 = rowptr[n + 1];
    float wd4 = wdot[4];
    float adn = ad2n[n];
    float den = 0.f;
    float acc[4] = {0.f, 0.f, 0.f, 0.f};
    const uint2* h2u2 = (const uint2*)h2h;

    for (int base = row0; base < row1; base += 64) {
        int j = base + lane;
        bool val = j < row1;
        int4 rc = val ? rec[j] : make_int4(0, 0, 0, 0);
        int sv = rc.x;
        float en = __int_as_float(rc.y);
        float a = as2n[sv] + adn + en * wd4;   // as2n: 400KB, L2-resident
        a = fmaxf(a, 0.2f*a);
        float p = val ? __expf(a) : 0.f;
        den += p;
        pl[wid][lane] = p;
        srcl[wid][lane] = sv;

        int cnt = min(64, row1 - base);
        for (int i = 0; i < cnt; i += 8) {
            int idx = i + es8;
            int se   = srcl[wid][idx];
            float ex = pl[wid][idx];
            uint2 u = h2u2[(size_t)se*8 + l3];     // 4 channels, 8B
            __half2 h01 = *(const __half2*)&u.x;
            __half2 h23 = *(const __half2*)&u.y;
            acc[0] = fmaf(ex, __half2float(__low2half(h01)),  acc[0]);
            acc[1] = fmaf(ex, __half2float(__high2half(h01)), acc[1]);
            acc[2] = fmaf(ex, __half2float(__low2half(h23)),  acc[2]);
            acc[3] = fmaf(ex, __half2float(__high2half(h23)), acc[3]);
        }
    }
    #pragma unroll
    for (int d = 32; d; d >>= 1) den += __shfl_xor(den, d);
    #pragma unroll
    for (int k = 0; k < 4; ++k) {
        acc[k] += __shfl_xor(acc[k], 8);
        acc[k] += __shfl_xor(acc[k], 16);
        acc[k] += __shfl_xor(acc[k], 32);
    }
    float r = 1.f / (den + 1e-16f);
    if (lane < 8) {
        float4 b2v = ((const float4*)b2)[l3];
        float z0 = acc[0]*r + b2v.x;
        float z1 = acc[1]*r + b2v.y;
        float z2 = acc[2]*r + b2v.z;
        float z3 = acc[3]*r + b2v.w;
        *(float4*)&out[(size_t)n*32 + 4*l3] = make_float4(z0, z1, z2, z3);
        zh2[wid][2*l3]     = __floats2half2_rn(z0, z1);
        zh2[wid][2*l3 + 1] = __floats2half2_rn(z2, z3);
    }
    // same-wave LDS: in-order, no barrier

    // t = elu(z@Wd1+bd1): fdot2, k-split across halves (8 pairs each)
    int kp0 = half * 8;
    float t2 = 0.f;
    #pragma unroll
    for (int k = 0; k < 8; ++k)
        t2 = fdot2f(zh2[wid][kp0 + k], Wd1h[(kp0 + k)*32 + l5], t2);
    t2 += __shfl_xor(t2, 32);
    t2 += bd1[l5];
    t2 = t2 > 0.f ? t2 : __expf(t2) - 1.f;
    // pack t into half2 pairs (lanes<16; t2 valid on lanes 0..31)
    float ta = __shfl(t2, 2*l4);
    float tb = __shfl(t2, 2*l4 + 1);
    if (lane < 16) th2[wid][l4] = __floats2half2_rn(ta, tb);
    // same-wave LDS: in-order, no barrier

    float xo = bd2[lane];
    #pragma unroll
    for (int k = 0; k < 16; ++k)
        xo = fdot2f(th2[wid][k], Wd2h[k*64 + lane], xo);
    out[(size_t)NN*32 + (size_t)n*64 + lane] = xo;
}

extern "C" void kernel_launch(void* const* d_in, const int* in_sizes, int n_in,
                              void* d_out, int out_size, void* d_ws, size_t ws_size,
                              hipStream_t stream) {
    const float* x    = (const float*)d_in[0];
    const int*   ei   = (const int*)  d_in[1];
    const float* ea   = (const float*)d_in[2];
    const float* bng  = (const float*)d_in[3];
    const float* bnb  = (const float*)d_in[4];
    const float* bnm  = (const float*)d_in[5];
    const float* bnv  = (const float*)d_in[6];
    const float* W1   = (const float*)d_in[7];
    const float* as1  = (const float*)d_in[8];
    const float* ad1  = (const float*)d_in[9];
    const float* We1  = (const float*)d_in[10];
    const float* ae1  = (const float*)d_in[11];
    const float* b1   = (const float*)d_in[12];
    const float* W2   = (const float*)d_in[13];
    const float* as2  = (const float*)d_in[14];
    const float* ad2  = (const float*)d_in[15];
    const float* We2  = (const float*)d_in[16];
    const float* ae2  = (const float*)d_in[17];
    const float* b2   = (const float*)d_in[18];
    const float* Wd1  = (const float*)d_in[19];
    const float* bd1  = (const float*)d_in[20];
    const float* Wd2  = (const float*)d_in[21];
    const float* bd2  = (const float*)d_in[22];
    float* out = (float*)d_out;

    char* wsb = (char*)d_ws;
    __half2* h1h = (__half2*)wsb;                          // NN*64*4B = 25.6MB
    float* as1n  = (float*)(wsb += (size_t)NN*64*4);       // NN*4
    float* ad1n  = (float*)(wsb += (size_t)NN*4*4);        // NN*4
    __half2* h2h = (__half2*)(wsb += (size_t)NN*4*4);      // NN*16*4B
    float* as2n  = (float*)(wsb += (size_t)NN*16*4);       // NN
    float* ad2n  = (float*)(wsb += (size_t)NN*4);          // NN
    float* wdot  = (float*)(wsb += (size_t)NN*4);          // 8
    int4* rec    = (int4*)(wsb += 8*4);                    // NE*16B
    int* rank    = (int*)(wsb += (size_t)NE*16);           // NE
    int* counts  = (int*)(wsb += (size_t)NE*4);            // NN
    int* rowptr  = (int*)(wsb += (size_t)NN*4);            // NN+1
    int* bsum    = (int*)(wsb += (size_t)(NN+1)*4);        // 64
    int* boff    = (int*)(wsb += 64*4);                    // 64

    hipMemsetAsync(counts, 0, NN * sizeof(int), stream);
    hipLaunchKernelGGL(k_hist, dim3((NE+255)/256), dim3(256), 0, stream, ei, counts, rank);
    hipLaunchKernelGGL(k_s1, dim3(49), dim3(256), 0, stream, counts, bsum);
    hipLaunchKernelGGL(k_s2, dim3(1), dim3(128), 0, stream,
                       bsum, boff, rowptr, We1, ae1, We2, ae2, wdot);
    hipLaunchKernelGGL(k_s3, dim3(49), dim3(256), 0, stream, counts, boff, rowptr);
    hipLaunchKernelGGL(k1_node1, dim3(1024), dim3(256), 0, stream,
                       x, W1, as1, ad1, h1h, as1n, ad1n);
    hipLaunchKernelGGL(k_scatter, dim3((NE+255)/256), dim3(256), 0, stream,
                       ei, ea, bng, bnb, bnm, bnv, rowptr, rank,
                       as1n, ad1n, wdot, rec);
    hipLaunchKernelGGL(kA1, dim3(NN/4), dim3(256), 0, stream,
                       rowptr, rec, h1h, b1, W2, as2, ad2, h2h, as2n, ad2n);
    hipLaunchKernelGGL(kA2, dim3(NN/4), dim3(256), 0, stream,
                       rowptr, rec, as2n, ad2n, wdot, h2h, b2, Wd1, bd1, Wd2, bd2,
                       out);
}

// Round 14
// 368.094 us; speedup vs baseline: 1.1924x; 1.0310x over previous
//
#include <hip/hip_runtime.h>
#include <hip/hip_fp16.h>
#include <math.h>

#define NN 100000
#define NE 1600000

typedef _Float16 h2v __attribute__((ext_vector_type(2)));
__device__ __forceinline__ float fdot2f(__half2 a, __half2 b, float c) {
#if __has_builtin(__builtin_amdgcn_fdot2)
    return __builtin_amdgcn_fdot2(*(h2v*)&a, *(h2v*)&b, c, false);
#else
    c = fmaf(__half2float(__low2half(a)),  __half2float(__low2half(b)),  c);
    c = fmaf(__half2float(__high2half(a)), __half2float(__high2half(b)), c);
    return c;
#endif
}

// ---------- CSR build: hist with rank recording ----------
__global__ void k_hist(const int* __restrict__ ei, int* __restrict__ counts,
                       int* __restrict__ rank) {
    int e = blockIdx.x * blockDim.x + threadIdx.x;
    if (e < NE) rank[e] = atomicAdd(&counts[ei[NE + e]], 1);
}

__global__ void k_s1(const int* __restrict__ counts, int* __restrict__ bsum) {
    __shared__ int sd[256];
    int tid = threadIdx.x, b = blockIdx.x;
    int base = b * 2048 + tid * 8;
    int s = 0;
    #pragma unroll
    for (int j = 0; j < 8; ++j) {
        int g = base + j;
        s += (g < NN) ? counts[g] : 0;
    }
    sd[tid] = s;
    __syncthreads();
    for (int d = 128; d; d >>= 1) {
        if (tid < d) sd[tid] += sd[tid + d];
        __syncthreads();
    }
    if (tid == 0) bsum[b] = sd[0];
}

__global__ void k_s2(const int* __restrict__ bsum, int* __restrict__ boff,
                     int* __restrict__ rowptr,
                     const float* __restrict__ We1, const float* __restrict__ ae1,
                     const float* __restrict__ We2, const float* __restrict__ ae2,
                     float* __restrict__ wdot) {
    int t = threadIdx.x;
    if (t == 0) {
        int run = 0;
        for (int b = 0; b < 49; ++b) { boff[b] = run; run += bsum[b]; }
        rowptr[NN] = NE;
    }
    if (t >= 64 && t < 68) {
        int h = t - 64;
        float s = 0.f;
        for (int c = 0; c < 32; ++c) s += We1[h*32+c] * ae1[h*32+c];
        wdot[h] = s;
    } else if (t == 68) {
        float s = 0.f;
        for (int c = 0; c < 32; ++c) s += We2[c] * ae2[c];
        wdot[4] = s;
    }
}

__global__ void k_s3(const int* __restrict__ counts, const int* __restrict__ boff,
                     int* __restrict__ rowptr) {
    __shared__ int sT[256];
    int tid = threadIdx.x, b = blockIdx.x;
    int base = b * 2048 + tid * 8;
    int c[8];
    int s = 0;
    #pragma unroll
    for (int j = 0; j < 8; ++j) {
        int g = base + j;
        c[j] = (g < NN) ? counts[g] : 0;
        s += c[j];
    }
    sT[tid] = s;
    __syncthreads();
    for (int d = 1; d < 256; d <<= 1) {
        int v = (tid >= d) ? sT[tid - d] : 0;
        __syncthreads();
        sT[tid] += v;
        __syncthreads();
    }
    int run = (tid ? sT[tid - 1] : 0) + boff[b];
    #pragma unroll
    for (int j = 0; j < 8; ++j) {
        int g = base + j;
        if (g < NN) rowptr[g] = run;
        run += c[j];
    }
}

// ---------- node transform L1: h1 fp16, alpha_src/dst ----------
__global__ void __launch_bounds__(256, 2)
k1_node1(const float* __restrict__ x, const float* __restrict__ W1,
         const float* __restrict__ as1, const float* __restrict__ ad1,
         __half2* __restrict__ h1h, float* __restrict__ as1n,
         float* __restrict__ ad1n) {
    int tid = threadIdx.x, wid = tid >> 6, lane = tid & 63;
    float wc0[64], wc1[64];
    #pragma unroll
    for (int k = 0; k < 64; ++k) {
        wc0[k] = W1[k*128 + 2*lane];
        wc1[k] = W1[k*128 + 2*lane + 1];
    }
    float asc0 = as1[2*lane], asc1 = as1[2*lane+1];
    float adc0 = ad1[2*lane], adc1 = ad1[2*lane+1];
    int gw = (blockIdx.x << 2) + wid;
    int nw = gridDim.x << 2;
    for (int n = gw; n < NN; n += nw) {
        int nu = __builtin_amdgcn_readfirstlane(n);
        const float* xr = x + (size_t)nu * 64;
        float a0 = 0.f, a1 = 0.f;
        #pragma unroll
        for (int k = 0; k < 64; ++k) {
            float xk = xr[k];
            a0 = fmaf(xk, wc0[k], a0);
            a1 = fmaf(xk, wc1[k], a1);
        }
        h1h[(size_t)nu*64 + lane] = __float22half2_rn(make_float2(a0, a1));
        float p = a0*asc0 + a1*asc1;
        float q = a0*adc0 + a1*adc1;
        #pragma unroll
        for (int d = 1; d < 16; d <<= 1) {
            p += __shfl_xor(p, d);
            q += __shfl_xor(q, d);
        }
        if ((lane & 15) == 0) {
            int h = lane >> 4;
            as1n[nu*4 + h] = p;
            ad1n[nu*4 + h] = q;
        }
    }
}

// ---------- scatter + L1 exp precompute: ONE int4 record per edge ----------
__global__ void k_scatter(const int* __restrict__ ei, const float* __restrict__ ea,
                          const float* __restrict__ g, const float* __restrict__ b,
                          const float* __restrict__ m, const float* __restrict__ v,
                          const int* __restrict__ rowptr, const int* __restrict__ rank,
                          const float* __restrict__ as1n, const float* __restrict__ ad1n,
                          const float* __restrict__ wdot, int4* __restrict__ rec) {
    int e = blockIdx.x * blockDim.x + threadIdx.x;
    if (e >= NE) return;
    int src = ei[e], dst = ei[NE + e];
    int pos = rowptr[dst] + rank[e];
    float en = (log1pf(ea[e]) - m[0]) * rsqrtf(v[0] + 1e-5f) * g[0] + b[0];
    float4 wd  = *(const float4*)wdot;
    float4 asv = *(const float4*)&as1n[src*4];
    float4 adv = *(const float4*)&ad1n[dst*4];
    float a0 = asv.x + adv.x + en*wd.x; a0 = fmaxf(a0, 0.2f*a0);
    float a1 = asv.y + adv.y + en*wd.y; a1 = fmaxf(a1, 0.2f*a1);
    float a2 = asv.z + adv.z + en*wd.z; a2 = fmaxf(a2, 0.2f*a2);
    float a3 = asv.w + adv.w + en*wd.w; a3 = fmaxf(a3, 0.2f*a3);
    __half2 p01 = __floats2half2_rn(__expf(a0), __expf(a1));
    __half2 p23 = __floats2half2_rn(__expf(a2), __expf(a3));
    int4 rc;
    rc.x = src;
    rc.y = __float_as_int(en);
    rc.z = *(const int*)&p01;
    rc.w = *(const int*)&p23;
    rec[pos] = rc;
}

// ---------- L1 aggregate: 2x-unrolled gather (8 edges in flight) ----------
__global__ void __launch_bounds__(256)
kA1(const int* __restrict__ rowptr, const int4* __restrict__ rec,
    const __half2* __restrict__ h1h,
    const float* __restrict__ b1, const float* __restrict__ W2,
    const float* __restrict__ as2, const float* __restrict__ ad2,
    __half2* __restrict__ h2h, float* __restrict__ as2n, float* __restrict__ ad2n) {
    __shared__ __half2 W2h[64*32];          // (k-pair, col): 8KB
    __shared__ float4 exs4[4][64];
    __shared__ int    srcl[4][64];
    __shared__ __half2 slot_h2[4][64];      // out1 as 64 channel-pairs per node
    int tid = threadIdx.x, wid = tid >> 6, lane = tid & 63;
    for (int i = tid; i < 2048; i += 256) {
        int k2 = i >> 5, c = i & 31;
        W2h[i] = __floats2half2_rn(W2[(2*k2)*32 + c], W2[(2*k2+1)*32 + c]);
    }
    __syncthreads();

    int n = blockIdx.x * 4 + wid;
    int row0 = rowptr[n], row1 = rowptr[n + 1];
    int es4 = lane >> 4;         // edge slot (0..3)
    int co  = lane & 15;         // channel oct: channels 8co..8co+7
    int hq4 = co >> 2;           // head of these channels
    float den0 = 0.f, den1 = 0.f, den2 = 0.f, den3 = 0.f;
    float acc[8] = {0.f,0.f,0.f,0.f,0.f,0.f,0.f,0.f};
    const float* exf = (const float*)&exs4[wid][0];
    const uint4* h1u4 = (const uint4*)h1h;

    for (int base = row0; base < row1; base += 64) {
        int j = base + lane;
        bool val = j < row1;
        int4 rc = val ? rec[j] : make_int4(0, 0, 0, 0);
        float2 e01 = __half22float2(*(const __half2*)&rc.z);
        float2 e23 = __half22float2(*(const __half2*)&rc.w);
        den0 += e01.x; den1 += e01.y; den2 += e23.x; den3 += e23.y;
        exs4[wid][lane] = make_float4(e01.x, e01.y, e23.x, e23.y);
        srcl[wid][lane] = rc.x;
        // same-wave LDS: in-order, no barrier; invalid lanes store ex=0,src=0
        // so idx beyond cnt is safe (ex=0 annihilates) - no inner guards.

        int cnt = min(64, row1 - base);
        int i = 0;
        for (; i + 4 < cnt; i += 8) {      // 2 independent 16B gathers in flight
            int idxA = i + es4, idxB = i + 4 + es4;
            int sA = srcl[wid][idxA];
            int sB = srcl[wid][idxB];
            float exA = exf[idxA*4 + hq4];
            float exB = exf[idxB*4 + hq4];
            uint4 uA = h1u4[(size_t)sA*16 + co];
            uint4 uB = h1u4[(size_t)sB*16 + co];
            __half2 a01 = *(const __half2*)&uA.x, a23 = *(const __half2*)&uA.y;
            __half2 a45 = *(const __half2*)&uA.z, a67 = *(const __half2*)&uA.w;
            acc[0] = fmaf(exA, __half2float(__low2half(a01)),  acc[0]);
            acc[1] = fmaf(exA, __half2float(__high2half(a01)), acc[1]);
            acc[2] = fmaf(exA, __half2float(__low2half(a23)),  acc[2]);
            acc[3] = fmaf(exA, __half2float(__high2half(a23)), acc[3]);
            acc[4] = fmaf(exA, __half2float(__low2half(a45)),  acc[4]);
            acc[5] = fmaf(exA, __half2float(__high2half(a45)), acc[5]);
            acc[6] = fmaf(exA, __half2float(__low2half(a67)),  acc[6]);
            acc[7] = fmaf(exA, __half2float(__high2half(a67)), acc[7]);
            __half2 b01 = *(const __half2*)&uB.x, b23 = *(const __half2*)&uB.y;
            __half2 b45 = *(const __half2*)&uB.z, b67 = *(const __half2*)&uB.w;
            acc[0] = fmaf(exB, __half2float(__low2half(b01)),  acc[0]);
            acc[1] = fmaf(exB, __half2float(__high2half(b01)), acc[1]);
            acc[2] = fmaf(exB, __half2float(__low2half(b23)),  acc[2]);
            acc[3] = fmaf(exB, __half2float(__high2half(b23)), acc[3]);
            acc[4] = fmaf(exB, __half2float(__low2half(b45)),  acc[4]);
            acc[5] = fmaf(exB, __half2float(__high2half(b45)), acc[5]);
            acc[6] = fmaf(exB, __half2float(__low2half(b67)),  acc[6]);
            acc[7] = fmaf(exB, __half2float(__high2half(b67)), acc[7]);
        }
        if (i < cnt) {                      // tail: <=4 edges
            int idx = i + es4;
            int s = srcl[wid][idx];
            float ex = exf[idx*4 + hq4];
            uint4 u = h1u4[(size_t)s*16 + co];
            __half2 h01 = *(const __half2*)&u.x, h23 = *(const __half2*)&u.y;
            __half2 h45 = *(const __half2*)&u.z, h67 = *(const __half2*)&u.w;
            acc[0] = fmaf(ex, __half2float(__low2half(h01)),  acc[0]);
            acc[1] = fmaf(ex, __half2float(__high2half(h01)), acc[1]);
            acc[2] = fmaf(ex, __half2float(__low2half(h23)),  acc[2]);
            acc[3] = fmaf(ex, __half2float(__high2half(h23)), acc[3]);
            acc[4] = fmaf(ex, __half2float(__low2half(h45)),  acc[4]);
            acc[5] = fmaf(ex, __half2float(__high2half(h45)), acc[5]);
            acc[6] = fmaf(ex, __half2float(__low2half(h67)),  acc[6]);
            acc[7] = fmaf(ex, __half2float(__high2half(h67)), acc[7]);
        }
    }
    // merge 4 edge-slot partials; reduce denominators wave-wide
    #pragma unroll
    for (int k = 0; k < 8; ++k) {
        acc[k] += __shfl_xor(acc[k], 16);
        acc[k] += __shfl_xor(acc[k], 32);
    }
    #pragma unroll
    for (int d = 32; d; d >>= 1) {
        den0 += __shfl_xor(den0, d); den1 += __shfl_xor(den1, d);
        den2 += __shfl_xor(den2, d); den3 += __shfl_xor(den3, d);
    }
    float dh = (hq4 == 0) ? den0 : (hq4 == 1) ? den1 : (hq4 == 2) ? den2 : den3;
    float r = 1.f / (dh + 1e-16f);
    // ALL lanes finalize 2 channels each: pair cp = 4*co + es4
    float accA = (es4 == 0) ? acc[0] : (es4 == 1) ? acc[2] : (es4 == 2) ? acc[4] : acc[6];
    float accB = (es4 == 0) ? acc[1] : (es4 == 1) ? acc[3] : (es4 == 2) ? acc[5] : acc[7];
    int cp = 4*co + es4;
    float2 bb = ((const float2*)b1)[cp];
    float oA = accA * r + bb.x;
    float oB = accB * r + bb.y;
    oA = oA > 0.f ? oA : __expf(oA) - 1.f;
    oB = oB > 0.f ? oB : __expf(oB) - 1.f;
    slot_h2[wid][cp] = __floats2half2_rn(oA, oB);
    // same-wave LDS: in-order, no barrier

    // h2 = elu(out1) @ W2 via fdot2, k-split across wave halves
    int es = lane >> 5, cq = lane & 31;
    int k2base = es * 32;
    float s2 = 0.f;
    #pragma unroll
    for (int kk = 0; kk < 32; ++kk)
        s2 = fdot2f(slot_h2[wid][k2base + kk], W2h[(k2base + kk)*32 + cq], s2);
    s2 += __shfl_xor(s2, 32);
    int l4 = lane & 15;
    float za = __shfl(s2, 2*l4);
    float zb = __shfl(s2, 2*l4 + 1);
    if (lane < 16) h2h[(size_t)n*16 + l4] = __float22half2_rn(make_float2(za, zb));
    float av = s2 * as2[cq] * 0.5f;
    float dv = s2 * ad2[cq] * 0.5f;
    #pragma unroll
    for (int d = 32; d; d >>= 1) { av += __shfl_xor(av, d); dv += __shfl_xor(dv, d); }
    if (lane == 0) { as2n[n] = av; ad2n[n] = dv; }
}

// ---------- L2 aggregate: 2x-unrolled gather + fdot2 decoder ----------
__global__ void __launch_bounds__(256)
kA2(const int* __restrict__ rowptr, const int4* __restrict__ rec,
    const float* __restrict__ as2n, const float* __restrict__ ad2n,
    const float* __restrict__ wdot, const __half2* __restrict__ h2h,
    const float* __restrict__ b2, const float* __restrict__ Wd1,
    const float* __restrict__ bd1, const float* __restrict__ Wd2,
    const float* __restrict__ bd2, float* __restrict__ out) {
    __shared__ __half2 Wd1h[16*32];         // 2KB
    __shared__ __half2 Wd2h[16*64];         // 4KB
    __shared__ float pl[4][64];
    __shared__ int   srcl[4][64];
    __shared__ __half2 zh2[4][16], th2[4][16];
    int tid = threadIdx.x, wid = tid >> 6, lane = tid & 63;
    int es8 = lane >> 3, l3 = lane & 7;
    int half = lane >> 5, l5 = lane & 31;
    int l4 = lane & 15;
    for (int i = tid; i < 512; i += 256) {
        int kp = i >> 5, c = i & 31;
        Wd1h[i] = __floats2half2_rn(Wd1[(2*kp)*32 + c], Wd1[(2*kp+1)*32 + c]);
    }
    for (int i = tid; i < 1024; i += 256) {
        int kp = i >> 6, c = i & 63;
        Wd2h[i] = __floats2half2_rn(Wd2[(2*kp)*64 + c], Wd2[(2*kp+1)*64 + c]);
    }
    __syncthreads();

    int n = blockIdx.x * 4 + wid;
    int row0 = rowptr[n], row1 = rowptr[n + 1];
    float wd4 = wdot[4];
    float adn = ad2n[n];
    float den = 0.f;
    float acc[4] = {0.f, 0.f, 0.f, 0.f};
    const uint2* h2u2 = (const uint2*)h2h;

    for (int base = row0; base < row1; base += 64) {
        int j = base + lane;
        bool val = j < row1;
        int4 rc = val ? rec[j] : make_int4(0, 0, 0, 0);
        int sv = rc.x;
        float en = __int_as_float(rc.y);
        float a = as2n[sv] + adn + en * wd4;   // as2n: 400KB, L2-resident
        a = fmaxf(a, 0.2f*a);
        float p = val ? __expf(a) : 0.f;
        den += p;
        pl[wid][lane] = p;
        srcl[wid][lane] = sv;

        int cnt = min(64, row1 - base);
        int i = 0;
        for (; i + 8 < cnt; i += 16) {      // 2 independent 8B gathers in flight
            int idxA = i + es8, idxB = i + 8 + es8;
            int sA = srcl[wid][idxA];
            int sB = srcl[wid][idxB];
            float exA = pl[wid][idxA];
            float exB = pl[wid][idxB];
            uint2 uA = h2u2[(size_t)sA*8 + l3];
            uint2 uB = h2u2[(size_t)sB*8 + l3];
            __half2 a01 = *(const __half2*)&uA.x, a23 = *(const __half2*)&uA.y;
            acc[0] = fmaf(exA, __half2float(__low2half(a01)),  acc[0]);
            acc[1] = fmaf(exA, __half2float(__high2half(a01)), acc[1]);
            acc[2] = fmaf(exA, __half2float(__low2half(a23)),  acc[2]);
            acc[3] = fmaf(exA, __half2float(__high2half(a23)), acc[3]);
            __half2 b01 = *(const __half2*)&uB.x, b23 = *(const __half2*)&uB.y;
            acc[0] = fmaf(exB, __half2float(__low2half(b01)),  acc[0]);
            acc[1] = fmaf(exB, __half2float(__high2half(b01)), acc[1]);
            acc[2] = fmaf(exB, __half2float(__low2half(b23)),  acc[2]);
            acc[3] = fmaf(exB, __half2float(__high2half(b23)), acc[3]);
        }
        if (i < cnt) {                      // tail: <=8 edges
            int idx = i + es8;
            int se = srcl[wid][idx];
            float ex = pl[wid][idx];
            uint2 u = h2u2[(size_t)se*8 + l3];
            __half2 h01 = *(const __half2*)&u.x, h23 = *(const __half2*)&u.y;
            acc[0] = fmaf(ex, __half2float(__low2half(h01)),  acc[0]);
            acc[1] = fmaf(ex, __half2float(__high2half(h01)), acc[1]);
            acc[2] = fmaf(ex, __half2float(__low2half(h23)),  acc[2]);
            acc[3] = fmaf(ex, __half2float(__high2half(h23)), acc[3]);
        }
    }
    #pragma unroll
    for (int d = 32; d; d >>= 1) den += __shfl_xor(den, d);
    #pragma unroll
    for (int k = 0; k < 4; ++k) {
        acc[k] += __shfl_xor(acc[k], 8);
        acc[k] += __shfl_xor(acc[k], 16);
        acc[k] += __shfl_xor(acc[k], 32);
    }
    float r = 1.f / (den + 1e-16f);
    if (lane < 8) {
        float4 b2v = ((const float4*)b2)[l3];
        float z0 = acc[0]*r + b2v.x;
        float z1 = acc[1]*r + b2v.y;
        float z2 = acc[2]*r + b2v.z;
        float z3 = acc[3]*r + b2v.w;
        *(float4*)&out[(size_t)n*32 + 4*l3] = make_float4(z0, z1, z2, z3);
        zh2[wid][2*l3]     = __floats2half2_rn(z0, z1);
        zh2[wid][2*l3 + 1] = __floats2half2_rn(z2, z3);
    }
    // same-wave LDS: in-order, no barrier

    // t = elu(z@Wd1+bd1): fdot2, k-split across halves (8 pairs each)
    int kp0 = half * 8;
    float t2 = 0.f;
    #pragma unroll
    for (int k = 0; k < 8; ++k)
        t2 = fdot2f(zh2[wid][kp0 + k], Wd1h[(kp0 + k)*32 + l5], t2);
    t2 += __shfl_xor(t2, 32);
    t2 += bd1[l5];
    t2 = t2 > 0.f ? t2 : __expf(t2) - 1.f;
    float ta = __shfl(t2, 2*l4);
    float tb = __shfl(t2, 2*l4 + 1);
    if (lane < 16) th2[wid][l4] = __floats2half2_rn(ta, tb);
    // same-wave LDS: in-order, no barrier

    float xo = bd2[lane];
    #pragma unroll
    for (int k = 0; k < 16; ++k)
        xo = fdot2f(th2[wid][k], Wd2h[k*64 + lane], xo);
    out[(size_t)NN*32 + (size_t)n*64 + lane] = xo;
}

extern "C" void kernel_launch(void* const* d_in, const int* in_sizes, int n_in,
                              void* d_out, int out_size, void* d_ws, size_t ws_size,
                              hipStream_t stream) {
    const float* x    = (const float*)d_in[0];
    const int*   ei   = (const int*)  d_in[1];
    const float* ea   = (const float*)d_in[2];
    const float* bng  = (const float*)d_in[3];
    const float* bnb  = (const float*)d_in[4];
    const float* bnm  = (const float*)d_in[5];
    const float* bnv  = (const float*)d_in[6];
    const float* W1   = (const float*)d_in[7];
    const float* as1  = (const float*)d_in[8];
    const float* ad1  = (const float*)d_in[9];
    const float* We1  = (const float*)d_in[10];
    const float* ae1  = (const float*)d_in[11];
    const float* b1   = (const float*)d_in[12];
    const float* W2   = (const float*)d_in[13];
    const float* as2  = (const float*)d_in[14];
    const float* ad2  = (const float*)d_in[15];
    const float* We2  = (const float*)d_in[16];
    const float* ae2  = (const float*)d_in[17];
    const float* b2   = (const float*)d_in[18];
    const float* Wd1  = (const float*)d_in[19];
    const float* bd1  = (const float*)d_in[20];
    const float* Wd2  = (const float*)d_in[21];
    const float* bd2  = (const float*)d_in[22];
    float* out = (float*)d_out;

    char* wsb = (char*)d_ws;
    __half2* h1h = (__half2*)wsb;                          // NN*64*4B = 25.6MB
    float* as1n  = (float*)(wsb += (size_t)NN*64*4);       // NN*4
    float* ad1n  = (float*)(wsb += (size_t)NN*4*4);        // NN*4
    __half2* h2h = (__half2*)(wsb += (size_t)NN*4*4);      // NN*16*4B
    float* as2n  = (float*)(wsb += (size_t)NN*16*4);       // NN
    float* ad2n  = (float*)(wsb += (size_t)NN*4);          // NN
    float* wdot  = (float*)(wsb += (size_t)NN*4);          // 8
    int4* rec    = (int4*)(wsb += 8*4);                    // NE*16B
    int* rank    = (int*)(wsb += (size_t)NE*16);           // NE
    int* counts  = (int*)(wsb += (size_t)NE*4);            // NN
    int* rowptr  = (int*)(wsb += (size_t)NN*4);            // NN+1
    int* bsum    = (int*)(wsb += (size_t)(NN+1)*4);        // 64
    int* boff    = (int*)(wsb += 64*4);                    // 64

    hipMemsetAsync(counts, 0, NN * sizeof(int), stream);
    hipLaunchKernelGGL(k_hist, dim3((NE+255)/256), dim3(256), 0, stream, ei, counts, rank);
    hipLaunchKernelGGL(k_s1, dim3(49), dim3(256), 0, stream, counts, bsum);
    hipLaunchKernelGGL(k_s2, dim3(1), dim3(128), 0, stream,
                       bsum, boff, rowptr, We1, ae1, We2, ae2, wdot);
    hipLaunchKernelGGL(k_s3, dim3(49), dim3(256), 0, stream, counts, boff, rowptr);
    hipLaunchKernelGGL(k1_node1, dim3(1024), dim3(256), 0, stream,
                       x, W1, as1, ad1, h1h, as1n, ad1n);
    hipLaunchKernelGGL(k_scatter, dim3((NE+255)/256), dim3(256), 0, stream,
                       ei, ea, bng, bnb, bnm, bnv, rowptr, rank,
                       as1n, ad1n, wdot, rec);
    hipLaunchKernelGGL(kA1, dim3(NN/4), dim3(256), 0, stream,
                       rowptr, rec, h1h, b1, W2, as2, ad2, h2h, as2n, ad2n);
    hipLaunchKernelGGL(kA2, dim3(NN/4), dim3(256), 0, stream,
                       rowptr, rec, as2n, ad2n, wdot, h2h, b2, Wd1, bd1, Wd2, bd2,
                       out);
}